// Round 1
// baseline (106.579 us; speedup 1.0000x reference)
//
#include <hip/hip_runtime.h>
#include <math.h>

// Problem constants (from reference): B=16384, IN=64, HID=128, OUT=1, E=64, NMAP=1000
#define B_N    16384
#define IN_D   64
#define HID_D  128
#define E_N    64
#define BPE    4                 // sample-range quarters per expert -> grid = 64*4 = 256 blocks
#define SCAN_N (B_N / BPE)       // 4096 samples scanned per block

// Block layout: 256 threads = 4 waves. Wave w owns hidden chunk [w*32, w*32+32).
// Lane l owns one sample per tile of 64. Expert is a pure function of blockIdx
// so all weight addresses are wave-uniform -> compiler emits s_load (scalar path)
// and v_fmac with an SGPR weight operand: zero VMEM/LDS traffic in the inner loop.
__global__ __launch_bounds__(256) void moe_fused(
    const float* __restrict__ x,
    const int*   __restrict__ num,
    const int*   __restrict__ c,
    const float* __restrict__ W1,
    const float* __restrict__ b1,
    const float* __restrict__ W2,
    const float* __restrict__ b2,
    float*       __restrict__ out)
{
    __shared__ int   s_list[1024];   // matched sample indices (avg ~64, cap generous)
    __shared__ int   s_cnt;
    __shared__ float s_part[4][64];  // per-wave partial y for cross-wave reduction

    const int tid    = threadIdx.x;
    const int expert = blockIdx.x & (E_N - 1);
    const int q      = blockIdx.x >> 6;

    if (tid == 0) s_cnt = 0;
    __syncthreads();

    // ---- Phase 1: scan our 4096-sample range, compact matches into LDS ----
    const int base = q * SCAN_N;
    for (int j = tid; j < SCAN_N; j += 256) {
        const int i = base + j;
        if (c[num[i]] == expert) {
            int p = atomicAdd(&s_cnt, 1);
            s_list[p & 1023] = i;
        }
    }
    __syncthreads();
    const int cnt = s_cnt;

    // ---- Phase 2: compute. wave id forced uniform for scalar weight loads ----
    const int wave = __builtin_amdgcn_readfirstlane(tid >> 6);
    const int lane = tid & 63;
    const int h0   = wave * 32;

    const float* We1   = W1 + (size_t)expert * (IN_D * HID_D) + h0;
    const float* be1   = b1 + expert * HID_D + h0;
    const float* We2   = W2 + expert * HID_D + h0;   // W2 is [E, HID, 1]
    const float  bias2 = b2[expert];

    for (int t = 0; t < cnt; t += 64) {
        const int  sidx   = t + lane;
        const bool valid  = (sidx < cnt);
        const int  sample = s_list[valid ? sidx : t];

        const float4* xp = (const float4*)(x + (size_t)sample * IN_D);

        float acc[32];
        #pragma unroll
        for (int h = 0; h < 32; ++h) acc[h] = 0.0f;

        // 16 iterations: 1 float4 x-load feeding 128 FMAs against scalar-loaded W1
        for (int v = 0; v < IN_D / 4; ++v) {
            const float4 f  = xp[v];
            const float* w0 = We1 + (4 * v + 0) * HID_D;
            const float* w1 = We1 + (4 * v + 1) * HID_D;
            const float* w2 = We1 + (4 * v + 2) * HID_D;
            const float* w3 = We1 + (4 * v + 3) * HID_D;
            #pragma unroll
            for (int h = 0; h < 32; ++h) acc[h] = fmaf(f.x, w0[h], acc[h]);
            #pragma unroll
            for (int h = 0; h < 32; ++h) acc[h] = fmaf(f.y, w1[h], acc[h]);
            #pragma unroll
            for (int h = 0; h < 32; ++h) acc[h] = fmaf(f.z, w2[h], acc[h]);
            #pragma unroll
            for (int h = 0; h < 32; ++h) acc[h] = fmaf(f.w, w3[h], acc[h]);
        }

        // bias + ReLU + fused second layer (OUT=1): partial y over this wave's 32 h
        float y = 0.0f;
        #pragma unroll
        for (int h = 0; h < 32; ++h) {
            float hv = acc[h] + be1[h];
            hv = hv > 0.0f ? hv : 0.0f;
            y = fmaf(hv, We2[h], y);
        }

        s_part[wave][lane] = y;
        __syncthreads();
        if (wave == 0 && valid) {
            const float tot = s_part[0][lane] + s_part[1][lane]
                            + s_part[2][lane] + s_part[3][lane] + bias2;
            out[sample] = 1.0f / (1.0f + expf(-tot));
        }
        __syncthreads();
    }
}

extern "C" void kernel_launch(void* const* d_in, const int* in_sizes, int n_in,
                              void* d_out, int out_size, void* d_ws, size_t ws_size,
                              hipStream_t stream)
{
    const float* x   = (const float*)d_in[0];
    const int*   num = (const int*)  d_in[1];
    const int*   c   = (const int*)  d_in[2];
    const float* W1  = (const float*)d_in[3];
    const float* b1  = (const float*)d_in[4];
    const float* W2  = (const float*)d_in[5];
    const float* b2  = (const float*)d_in[6];
    float*       out = (float*)d_out;

    moe_fused<<<dim3(E_N * BPE), dim3(256), 0, stream>>>(x, num, c, W1, b1, W2, b2, out);
}

// Round 2
// 95.809 us; speedup vs baseline: 1.1124x; 1.1124x over previous
//
#include <hip/hip_runtime.h>
#include <math.h>

// B=16384, IN=64, HID=128, OUT=1, E=64, NMAP=1000 (fp32 end-to-end)
#define B_N    16384
#define IN_D   64
#define HID_D  128
#define E_N    64
#define BPE    4                  // grid = 64 experts * 4 sample-quarters = 256 blocks
#define SCAN_N (B_N / BPE)        // 4096 samples scanned per block
#define PER_T  (SCAN_N / 256)     // 16 samples scanned per thread
#define LIST_CAP 2048

// Block = 256 threads = 4 waves. Wave w owns hidden chunk [w*32, w*32+32).
// W1[expert] staged in LDS (32KB); inner-loop weight reads are wave-uniform
// ds_read_b128 broadcasts (conflict-free). acc[32] statically indexed ->
// stays in VGPRs (round-1's scalar-path version demoted it: VGPR_Count=24).
__global__ __launch_bounds__(256) void moe_fused(
    const float* __restrict__ x,
    const int*   __restrict__ num,
    const int*   __restrict__ c,
    const float* __restrict__ W1,
    const float* __restrict__ b1,
    const float* __restrict__ W2,
    const float* __restrict__ b2,
    float*       __restrict__ out)
{
    __shared__ float w1s[IN_D * HID_D];   // 32 KB
    __shared__ float w2s[HID_D];
    __shared__ float b1s[HID_D];
    __shared__ int   s_list[LIST_CAP];    // 8 KB
    __shared__ int   s_cnt;
    __shared__ float s_part[4][64];

    const int tid    = threadIdx.x;
    const int expert = blockIdx.x & (E_N - 1);
    const int q      = blockIdx.x >> 6;

    if (tid == 0) s_cnt = 0;

    // ---- Prologue: all long-latency loads issued up front, independently ----
    // (a) W1 staging loads (32KB, coalesced float4)
    const float4* W1v = (const float4*)(W1 + (size_t)expert * (IN_D * HID_D));
    float4 wst[8];
    #pragma unroll
    for (int i = 0; i < 8; ++i) wst[i] = W1v[tid + 256 * i];

    // (b) scan: 16 independent coalesced num loads
    const int base = q * SCAN_N + tid;
    int nums[PER_T];
    #pragma unroll
    for (int it = 0; it < PER_T; ++it) nums[it] = num[base + it * 256];

    // (c) park W1 into LDS
    float4* w1v = (float4*)w1s;
    #pragma unroll
    for (int i = 0; i < 8; ++i) w1v[tid + 256 * i] = wst[i];

    // (d) 16 independent c gathers (c is 4KB -> L1/L2 resident)
    int es[PER_T];
    #pragma unroll
    for (int it = 0; it < PER_T; ++it) es[it] = c[nums[it]];

    // (e) small parameter stages
    if (tid < HID_D) w2s[tid] = W2[expert * HID_D + tid];
    else             b1s[tid - HID_D] = b1[expert * HID_D + (tid - HID_D)];

    __syncthreads();   // s_cnt init visible before appends

    #pragma unroll
    for (int it = 0; it < PER_T; ++it) {
        if (es[it] == expert) {
            int p = atomicAdd(&s_cnt, 1);
            if (p < LIST_CAP) s_list[p] = base + it * 256;
        }
    }
    __syncthreads();
    const int cnt = min(s_cnt, LIST_CAP);

    // ---- Compute: lane = sample, wave = 32-wide h chunk ----
    const int wave = __builtin_amdgcn_readfirstlane(tid >> 6);
    const int lane = tid & 63;
    const int h0   = wave * 32;
    const float b2v = b2[expert];

    for (int t = 0; t < cnt; t += 64) {
        const int  sidx   = t + lane;
        const bool valid  = (sidx < cnt);
        const int  sample = s_list[valid ? sidx : (cnt - 1)];

        const float4* xp = (const float4*)(x + (size_t)sample * IN_D);

        float acc[32];
        #pragma unroll
        for (int h = 0; h < 32; ++h) acc[h] = 0.0f;

        #pragma unroll 4
        for (int v = 0; v < IN_D / 4; ++v) {
            const float4 f = xp[v];
            const float fk[4] = { f.x, f.y, f.z, f.w };
            #pragma unroll
            for (int u = 0; u < 4; ++u) {
                const float4* wr = (const float4*)&w1s[(4 * v + u) * HID_D + h0];
                #pragma unroll
                for (int g = 0; g < 8; ++g) {
                    const float4 w = wr[g];
                    acc[4 * g + 0] = fmaf(fk[u], w.x, acc[4 * g + 0]);
                    acc[4 * g + 1] = fmaf(fk[u], w.y, acc[4 * g + 1]);
                    acc[4 * g + 2] = fmaf(fk[u], w.z, acc[4 * g + 2]);
                    acc[4 * g + 3] = fmaf(fk[u], w.w, acc[4 * g + 3]);
                }
            }
        }

        // bias + ReLU + fused layer 2 (OUT=1): partial y over this wave's 32 h
        float y = 0.0f;
        #pragma unroll
        for (int h = 0; h < 32; ++h) {
            float hv = acc[h] + b1s[h0 + h];
            hv = fmaxf(hv, 0.0f);
            y = fmaf(hv, w2s[h0 + h], y);
        }

        s_part[wave][lane] = y;
        __syncthreads();
        if (wave == 0 && valid) {
            const float tot = s_part[0][lane] + s_part[1][lane]
                            + s_part[2][lane] + s_part[3][lane] + b2v;
            out[sample] = 1.0f / (1.0f + expf(-tot));
        }
        __syncthreads();
    }
}

extern "C" void kernel_launch(void* const* d_in, const int* in_sizes, int n_in,
                              void* d_out, int out_size, void* d_ws, size_t ws_size,
                              hipStream_t stream)
{
    const float* x   = (const float*)d_in[0];
    const int*   num = (const int*)  d_in[1];
    const int*   c   = (const int*)  d_in[2];
    const float* W1  = (const float*)d_in[3];
    const float* b1  = (const float*)d_in[4];
    const float* W2  = (const float*)d_in[5];
    const float* b2  = (const float*)d_in[6];
    float*       out = (float*)d_out;

    moe_fused<<<dim3(E_N * BPE), dim3(256), 0, stream>>>(x, num, c, W1, b1, W2, b2, out);
}

// Round 3
// 80.250 us; speedup vs baseline: 1.3281x; 1.1939x over previous
//
#include <hip/hip_runtime.h>
#include <math.h>

// B=16384, IN=64, HID=128, OUT=1, E=64, NMAP=1000 (fp32 in/out; bf16 MFMA inside)
#define B_N    16384
#define IN_D   64
#define HID_D  128
#define E_N    64
#define BPE    4                  // grid = 64 experts * 4 sample-quarters = 256 blocks
#define SCAN_N (B_N / BPE)        // 4096 samples scanned per block
#define PER_T  (SCAN_N / 256)     // 16 per thread
#define CAP    512                // sample-list capacity (8x the 64 mean; max ~160)

typedef __attribute__((ext_vector_type(8))) short v8s;   // 8 bf16 (4 VGPRs)
typedef __attribute__((ext_vector_type(4))) float v4f;   // MFMA C/D

__device__ __forceinline__ short f2bf(float f) {         // fp32 -> bf16, RNE
    unsigned int u = __float_as_uint(f);
    u += 0x7fffu + ((u >> 16) & 1u);
    return (short)(u >> 16);
}

// Block = 256 threads = 4 waves. Wave w owns h in [32w, 32w+32) (2 MFMA n-tiles).
// B-frags (W1 cols, verified layout B[n=lane&15][k=quad*8+j]) built once from
// global, resident in 16 VGPRs. Per 16-sample M-tile: 4 dwordx4 x-loads ->
// 2 A-frags -> 4 MFMA -> fused ReLU*W2 + 16-lane shuffle reduce. No LDS in
// the compute loop (round-2's broadcast ds_read_b128 burned ~25k cyc/tile).
__global__ __launch_bounds__(256) void moe_mfma(
    const float* __restrict__ x,
    const int*   __restrict__ num,
    const int*   __restrict__ c,
    const float* __restrict__ W1,
    const float* __restrict__ b1,
    const float* __restrict__ W2,
    const float* __restrict__ b2,
    float*       __restrict__ out)
{
    __shared__ int   s_list[CAP];
    __shared__ int   s_cnt;
    __shared__ float s_yw[4][CAP];   // per-wave partial y (race-free, no atomics)

    const int tid    = threadIdx.x;
    const int expert = blockIdx.x & (E_N - 1);
    const int q      = blockIdx.x >> 6;
    if (tid == 0) s_cnt = 0;

    const int wave = __builtin_amdgcn_readfirstlane(tid >> 6);
    const int lane = tid & 63;
    const int l16  = lane & 15;
    const int quad = lane >> 4;

    // ---- B-fragments from global, once per block (k-major W1: stride HID) ----
    const float* W1e = W1 + (size_t)expert * (IN_D * HID_D);
    v8s bfrag[2][2];
    #pragma unroll
    for (int nt = 0; nt < 2; ++nt) {
        const int h = 32 * wave + 16 * nt + l16;
        #pragma unroll
        for (int kh = 0; kh < 2; ++kh)
            #pragma unroll
            for (int j = 0; j < 8; ++j)
                bfrag[nt][kh][j] = f2bf(W1e[(32 * kh + 8 * quad + j) * HID_D + h]);
    }
    const int   h0   = 32 * wave + l16, h1 = h0 + 16;
    const float b1v0 = b1[expert * HID_D + h0], b1v1 = b1[expert * HID_D + h1];
    const float w2v0 = W2[expert * HID_D + h0], w2v1 = W2[expert * HID_D + h1];
    const float b2v  = b2[expert];

    // ---- scan: independent num loads, then independent c gathers ----
    const int base = q * SCAN_N + tid;
    int nums[PER_T];
    #pragma unroll
    for (int it = 0; it < PER_T; ++it) nums[it] = num[base + it * 256];
    int es[PER_T];
    #pragma unroll
    for (int it = 0; it < PER_T; ++it) es[it] = c[nums[it]];

    __syncthreads();   // s_cnt init visible
    #pragma unroll
    for (int it = 0; it < PER_T; ++it) {
        if (es[it] == expert) {
            int p = atomicAdd(&s_cnt, 1);
            if (p < CAP) s_list[p] = base + it * 256;
        }
    }
    __syncthreads();
    const int cnt    = min(s_cnt, CAP);
    const int ntiles = (cnt + 15) >> 4;

    // ---- M-tiles of 16 samples ----
    for (int mt = 0; mt < ntiles; ++mt) {
        const int idx = mt * 16 + l16;
        const int s   = s_list[min(idx, cnt - 1)];
        const float4* row = (const float4*)(x + (size_t)s * IN_D);

        // A[m=l16][k=quad*8+j] (+32 for second k-half): 16 floats/lane
        const float4 f0 = row[2 * quad], f1 = row[2 * quad + 1];
        const float4 f2 = row[8 + 2 * quad], f3 = row[8 + 2 * quad + 1];
        v8s a0, a1;
        a0[0]=f2bf(f0.x); a0[1]=f2bf(f0.y); a0[2]=f2bf(f0.z); a0[3]=f2bf(f0.w);
        a0[4]=f2bf(f1.x); a0[5]=f2bf(f1.y); a0[6]=f2bf(f1.z); a0[7]=f2bf(f1.w);
        a1[0]=f2bf(f2.x); a1[1]=f2bf(f2.y); a1[2]=f2bf(f2.z); a1[3]=f2bf(f2.w);
        a1[4]=f2bf(f3.x); a1[5]=f2bf(f3.y); a1[6]=f2bf(f3.z); a1[7]=f2bf(f3.w);

        v4f acc0 = {0.f, 0.f, 0.f, 0.f};
        v4f acc1 = {0.f, 0.f, 0.f, 0.f};
        acc0 = __builtin_amdgcn_mfma_f32_16x16x32_bf16(a0, bfrag[0][0], acc0, 0, 0, 0);
        acc0 = __builtin_amdgcn_mfma_f32_16x16x32_bf16(a1, bfrag[0][1], acc0, 0, 0, 0);
        acc1 = __builtin_amdgcn_mfma_f32_16x16x32_bf16(a0, bfrag[1][0], acc1, 0, 0, 0);
        acc1 = __builtin_amdgcn_mfma_f32_16x16x32_bf16(a1, bfrag[1][1], acc1, 0, 0, 0);

        // C/D: col(h)=lane&15, row(sample)=quad*4+r. Fuse bias+ReLU+W2, reduce h.
        #pragma unroll
        for (int r = 0; r < 4; ++r) {
            float v = fmaxf(acc0[r] + b1v0, 0.f) * w2v0
                    + fmaxf(acc1[r] + b1v1, 0.f) * w2v1;
            v += __shfl_xor(v, 1);
            v += __shfl_xor(v, 2);
            v += __shfl_xor(v, 4);
            v += __shfl_xor(v, 8);
            if (l16 == 0) s_yw[wave][mt * 16 + quad * 4 + r] = v;
        }
    }
    __syncthreads();

    // ---- combine 4 wave-partials, sigmoid, scatter-store ----
    for (int i = tid; i < cnt; i += 256) {
        const float t = s_yw[0][i] + s_yw[1][i] + s_yw[2][i] + s_yw[3][i] + b2v;
        out[s_list[i]] = 1.0f / (1.0f + expf(-t));
    }
}

extern "C" void kernel_launch(void* const* d_in, const int* in_sizes, int n_in,
                              void* d_out, int out_size, void* d_ws, size_t ws_size,
                              hipStream_t stream)
{
    const float* x   = (const float*)d_in[0];
    const int*   num = (const int*)  d_in[1];
    const int*   c   = (const int*)  d_in[2];
    const float* W1  = (const float*)d_in[3];
    const float* b1  = (const float*)d_in[4];
    const float* W2  = (const float*)d_in[5];
    const float* b2  = (const float*)d_in[6];
    float*       out = (float*)d_out;

    moe_mfma<<<dim3(E_N * BPE), dim3(256), 0, stream>>>(x, num, c, W1, b1, W2, b2, out);
}

// Round 4
// 74.321 us; speedup vs baseline: 1.4340x; 1.0798x over previous
//
#include <hip/hip_runtime.h>
#include <math.h>

// B=16384, IN=64, HID=128, OUT=1, E=64, NMAP=1000 (fp32 in/out; bf16 MFMA inside)
#define B_N    16384
#define IN_D   64
#define HID_D  128
#define E_N    64
#define BPE    16                 // grid = 64 experts * 16 sample-slices = 1024 blocks
                                  //   -> 4 blocks/CU (round 3's BPE=4 gave 1/CU: all
                                  //      latency exposed, kernel ~23us at 8% occupancy)
#define SCAN_N (B_N / BPE)        // 1024 samples scanned per block
#define PER_T  (SCAN_N / 256)     // 4 per thread
#define CAP    256                // per-block list cap (mean ~16, max expert ~460/16)

typedef __attribute__((ext_vector_type(8))) short v8s;   // 8 bf16 (4 VGPRs)
typedef __attribute__((ext_vector_type(4))) float v4f;   // MFMA C/D

__device__ __forceinline__ short f2bf(float f) {         // fp32 -> bf16, RNE
    unsigned int u = __float_as_uint(f);
    u += 0x7fffu + ((u >> 16) & 1u);
    return (short)(u >> 16);
}

// Block = 256 threads = 4 waves. Wave w owns h in [32w, 32w+32) (2 MFMA n-tiles).
// B-frags (W1 cols, layout B[n=lane&15][k=quad*8+j]) built once from global,
// resident in 16 VGPRs. Per 16-sample M-tile: 4 dwordx4 x-loads -> 2 A-frags ->
// 4 MFMA -> fused bias/ReLU/W2 + 16-lane shuffle reduce; one cross-wave LDS
// combine at the end. No LDS in the compute loop.
__global__ __launch_bounds__(256) void moe_mfma(
    const float* __restrict__ x,
    const int*   __restrict__ num,
    const int*   __restrict__ c,
    const float* __restrict__ W1,
    const float* __restrict__ b1,
    const float* __restrict__ W2,
    const float* __restrict__ b2,
    float*       __restrict__ out)
{
    __shared__ int   s_list[CAP];
    __shared__ int   s_cnt;
    __shared__ float s_yw[4][CAP];   // per-wave partial y (race-free, no atomics)

    const int tid    = threadIdx.x;
    const int expert = blockIdx.x & (E_N - 1);
    const int q      = blockIdx.x >> 6;
    if (tid == 0) s_cnt = 0;

    const int wave = __builtin_amdgcn_readfirstlane(tid >> 6);
    const int lane = tid & 63;
    const int l16  = lane & 15;
    const int quad = lane >> 4;

    // ---- scan loads issued first (deepest latency), then frag build ----
    const int base = q * SCAN_N + tid;
    int nums[PER_T];
    #pragma unroll
    for (int it = 0; it < PER_T; ++it) nums[it] = num[base + it * 256];

    // ---- B-fragments from global (k-major W1: row stride HID_D) ----
    const float* W1e = W1 + (size_t)expert * (IN_D * HID_D);
    v8s bfrag[2][2];
    #pragma unroll
    for (int nt = 0; nt < 2; ++nt) {
        const int h = 32 * wave + 16 * nt + l16;
        #pragma unroll
        for (int kh = 0; kh < 2; ++kh)
            #pragma unroll
            for (int j = 0; j < 8; ++j)
                bfrag[nt][kh][j] = f2bf(W1e[(32 * kh + 8 * quad + j) * HID_D + h]);
    }
    const int   h0   = 32 * wave + l16, h1 = h0 + 16;
    const float b1v0 = b1[expert * HID_D + h0], b1v1 = b1[expert * HID_D + h1];
    const float w2v0 = W2[expert * HID_D + h0], w2v1 = W2[expert * HID_D + h1];
    const float b2v  = b2[expert];

    int es[PER_T];
    #pragma unroll
    for (int it = 0; it < PER_T; ++it) es[it] = c[nums[it]];

    __syncthreads();   // s_cnt init visible
    #pragma unroll
    for (int it = 0; it < PER_T; ++it) {
        if (es[it] == expert) {
            int p = atomicAdd(&s_cnt, 1);
            if (p < CAP) s_list[p] = base + it * 256;
        }
    }
    __syncthreads();
    const int cnt    = min(s_cnt, CAP);
    const int ntiles = (cnt + 15) >> 4;   // cnt==0 -> 0 tiles, loops skip safely

    // ---- M-tiles of 16 samples ----
    for (int mt = 0; mt < ntiles; ++mt) {
        const int idx = mt * 16 + l16;
        const int s   = s_list[min(idx, cnt - 1)];
        const float4* row = (const float4*)(x + (size_t)s * IN_D);

        // A[m=l16][k=quad*8+j] (+32 for second k-half): 16 floats/lane
        const float4 f0 = row[2 * quad],     f1 = row[2 * quad + 1];
        const float4 f2 = row[8 + 2 * quad], f3 = row[8 + 2 * quad + 1];
        v8s a0, a1;
        a0[0]=f2bf(f0.x); a0[1]=f2bf(f0.y); a0[2]=f2bf(f0.z); a0[3]=f2bf(f0.w);
        a0[4]=f2bf(f1.x); a0[5]=f2bf(f1.y); a0[6]=f2bf(f1.z); a0[7]=f2bf(f1.w);
        a1[0]=f2bf(f2.x); a1[1]=f2bf(f2.y); a1[2]=f2bf(f2.z); a1[3]=f2bf(f2.w);
        a1[4]=f2bf(f3.x); a1[5]=f2bf(f3.y); a1[6]=f2bf(f3.z); a1[7]=f2bf(f3.w);

        v4f acc0 = {0.f, 0.f, 0.f, 0.f};
        v4f acc1 = {0.f, 0.f, 0.f, 0.f};
        acc0 = __builtin_amdgcn_mfma_f32_16x16x32_bf16(a0, bfrag[0][0], acc0, 0, 0, 0);
        acc0 = __builtin_amdgcn_mfma_f32_16x16x32_bf16(a1, bfrag[0][1], acc0, 0, 0, 0);
        acc1 = __builtin_amdgcn_mfma_f32_16x16x32_bf16(a0, bfrag[1][0], acc1, 0, 0, 0);
        acc1 = __builtin_amdgcn_mfma_f32_16x16x32_bf16(a1, bfrag[1][1], acc1, 0, 0, 0);

        // C/D: col(h)=lane&15, row(sample)=quad*4+r. Fuse bias+ReLU+W2, reduce h.
        #pragma unroll
        for (int r = 0; r < 4; ++r) {
            float v = fmaxf(acc0[r] + b1v0, 0.f) * w2v0
                    + fmaxf(acc1[r] + b1v1, 0.f) * w2v1;
            v += __shfl_xor(v, 1);
            v += __shfl_xor(v, 2);
            v += __shfl_xor(v, 4);
            v += __shfl_xor(v, 8);
            if (l16 == 0) s_yw[wave][mt * 16 + quad * 4 + r] = v;
        }
    }
    __syncthreads();

    // ---- combine 4 wave-partials, sigmoid, scatter-store ----
    for (int i = tid; i < cnt; i += 256) {
        const float t = s_yw[0][i] + s_yw[1][i] + s_yw[2][i] + s_yw[3][i] + b2v;
        out[s_list[i]] = 1.0f / (1.0f + expf(-t));
    }
}

extern "C" void kernel_launch(void* const* d_in, const int* in_sizes, int n_in,
                              void* d_out, int out_size, void* d_ws, size_t ws_size,
                              hipStream_t stream)
{
    const float* x   = (const float*)d_in[0];
    const int*   num = (const int*)  d_in[1];
    const int*   c   = (const int*)  d_in[2];
    const float* W1  = (const float*)d_in[3];
    const float* b1  = (const float*)d_in[4];
    const float* W2  = (const float*)d_in[5];
    const float* b2  = (const float*)d_in[6];
    float*       out = (float*)d_out;

    moe_mfma<<<dim3(E_N * BPE), dim3(256), 0, stream>>>(x, num, c, W1, b1, W2, b2, out);
}